// Round 6
// baseline (978.708 us; speedup 1.0000x reference)
//
#include <hip/hip_runtime.h>
#include <hip/hip_bf16.h>

// GeneralConv: out[i[e]] += (group-wise 16x16 GEMV, weight slice k[e]) of input[j[e]], + bias.
// N=100000, E=2000000, C=64, K=27, G=4.
//
// R6: sort edges by (node_block=i>>7, k) instead of by i.
//  - k-runs -> each lane's weight slice (64B) is REGISTER-resident: zero LDS
//    weight traffic (was 2KB/edge + 1.6e7 bank conflicts).
//  - each 128-node block owns an exclusive 32KB LDS accumulator: per-edge
//    sums go through ds_add_f32 (och-indexed, 2-way alias = free); zero
//    global atomics; output is one coalesced bias-added writeout per block.
//  - no register accumulator carried across edges -> every edge independent,
//    compiler free to overlap x-gather latency.
//  - records shrink to 4B (j | i_local<<17): fill's scatter RMW halves.
// Half-wave per edge retained from R5 (x L1-return = 1KB/edge).

#define KPOS 27
#define NB 128                        // nodes per gather block (32KB acc)
#define WPACK_UINTS (KPOS * 512)     // [k][q][gc][m] bf16-pairs: 13824 uints = 55296 B
#define SCAN_NB 256                   // blocks in multi-block scan

typedef unsigned u32x4 __attribute__((ext_vector_type(4)));

__device__ __forceinline__ unsigned packbf(float a, float b) {
    unsigned ua = (unsigned)__bfloat16_as_ushort(__float2bfloat16(a));
    unsigned ub = (unsigned)__bfloat16_as_ushort(__float2bfloat16(b));
    return ua | (ub << 16);
}

// acc += bf16lo(x)*bf16lo(w) + bf16hi(x)*bf16hi(w)  -- one VOP3P instruction
#define DOT2(A, X, W) asm("v_dot2_f32_bf16 %0, %1, %2, %0" : "+v"(A) : "v"(X), "v"(W))

// ---------- fallback (used only if ws too small) ----------
__global__ void init_out_kernel(float* __restrict__ out, const float* __restrict__ bias, int total) {
    int idx = blockIdx.x * blockDim.x + threadIdx.x;
    if (idx < total) out[idx] = bias[idx & 63];
}
__global__ void edge_kernel_rawW(const float* __restrict__ input, const int* __restrict__ ei,
                                 const int* __restrict__ ej, const int* __restrict__ ek,
                                 const float* __restrict__ weight, float* __restrict__ out, int n_edges) {
    const int lane = threadIdx.x & 63;
    const int g16 = lane & 48;
    const int d = lane & 15;
    int wave = (blockIdx.x * blockDim.x + threadIdx.x) >> 6;
    int n_waves = (gridDim.x * blockDim.x) >> 6;
    for (int e = wave; e < n_edges; e += n_waves) {
        int ie = ei[e], je = ej[e], ke = ek[e];
        float x = input[je * 64 + lane];
        float acc = 0.0f;
        #pragma unroll
        for (int c = 0; c < 16; ++c)
            acc += __shfl(x, g16 + c, 64) * weight[(g16 + c) * 432 + d * 27 + ke];
        atomicAdd(out + ie * 64 + lane, acc);
    }
}

// ---------- fused prep: zero bucket counts, repack weights, convert x ----------
__global__ void prep_kernel(const float* __restrict__ input, const float* __restrict__ weight,
                            unsigned* __restrict__ xb, unsigned* __restrict__ wp,
                            int* __restrict__ cnt, int nbk, int nquads) {
    int t = blockIdx.x * blockDim.x + threadIdx.x;
    if (t < nbk) cnt[t] = 0;
    if (t < WPACK_UINTS) {
        int k  = t >> 9;
        int r  = t & 511;
        int q  = r >> 8;
        int r2 = r & 255;
        int gc = r2 >> 2;
        int m  = r2 & 3;
        int g = gc >> 4, d = gc & 15;
        int c = (q * 4 + m) * 2;
        int ic = g * 16 + c;
        float f0 = weight[ic * 432 + d * 27 + k];
        float f1 = weight[(ic + 1) * 432 + d * 27 + k];
        wp[t] = packbf(f0, f1);
    }
    if (t < nquads) {
        const float4* in4 = (const float4*)input;
        float4 a = in4[2 * t], b = in4[2 * t + 1];
        uint4 o;
        o.x = packbf(a.x, a.y);
        o.y = packbf(a.z, a.w);
        o.z = packbf(b.x, b.y);
        o.w = packbf(b.z, b.w);
        ((uint4*)xb)[t] = o;
    }
}

// ---------- sort pipeline (key = (i>>7)*27 + k) ----------
__global__ void rank_kernel(const int* __restrict__ ei, const int* __restrict__ ek,
                            int* __restrict__ cnt,
                            unsigned short* __restrict__ rank, int n_edges) {
    int e = blockIdx.x * blockDim.x + threadIdx.x;
    if (e < n_edges) {
        int bkt = (ei[e] >> 7) * KPOS + ek[e];
        rank[e] = (unsigned short)atomicAdd(&cnt[bkt], 1);
    }
}

// phase A: per-block partial sums of cnt chunks
__global__ void scanA_kernel(const int* __restrict__ cnt, int* __restrict__ partial,
                             int n, int chunk) {
    __shared__ int red[256];
    int b = blockIdx.x;
    int lo = b * chunk, hi = min(lo + chunk, n);
    int s = 0;
    for (int v = lo + threadIdx.x; v < hi; v += 256) s += cnt[v];
    red[threadIdx.x] = s;
    __syncthreads();
    for (int d = 128; d > 0; d >>= 1) {
        if (threadIdx.x < d) red[threadIdx.x] += red[threadIdx.x + d];
        __syncthreads();
    }
    if (threadIdx.x == 0) partial[b] = red[0];
}

// phase B: single tiny block scans SCAN_NB partials (exclusive), writes off[n]=total
__global__ void scanB_kernel(int* __restrict__ partial, int* __restrict__ off, int n) {
    __shared__ int sums[SCAN_NB];
    int t = threadIdx.x;
    sums[t] = partial[t];
    __syncthreads();
    for (int d = 1; d < SCAN_NB; d <<= 1) {
        int val = (t >= d) ? sums[t - d] : 0;
        __syncthreads();
        sums[t] += val;
        __syncthreads();
    }
    partial[t] = (t == 0) ? 0 : sums[t - 1];   // exclusive
    if (t == SCAN_NB - 1) off[n] = sums[t];
}

// phase C: per-block exclusive scan of its chunk, offset by partial[b]
__global__ void scanC_kernel(const int* __restrict__ cnt, const int* __restrict__ partial,
                             int* __restrict__ off, int n, int chunk) {
    __shared__ int excl[256];
    int b = blockIdx.x;
    int lo = b * chunk, hi = min(lo + chunk, n);
    int per = (chunk + 255) >> 8;
    int tlo = lo + threadIdx.x * per;
    int thi = min(tlo + per, hi);
    int s = 0;
    for (int v = tlo; v < thi; ++v) s += cnt[v];
    excl[threadIdx.x] = s;
    __syncthreads();
    for (int d = 1; d < 256; d <<= 1) {
        int val = (threadIdx.x >= d) ? excl[threadIdx.x - d] : 0;
        __syncthreads();
        excl[threadIdx.x] += val;
        __syncthreads();
    }
    int run = partial[b] + ((threadIdx.x == 0) ? 0 : excl[threadIdx.x - 1]);
    for (int v = tlo; v < thi; ++v) { off[v] = run; run += cnt[v]; }
}

// fill: 4-byte record per edge: j | (i_local << 17)
__global__ void fill_kernel(const int* __restrict__ ei, const int* __restrict__ ej,
                            const int* __restrict__ ek, const int* __restrict__ off,
                            const unsigned short* __restrict__ rank,
                            unsigned* __restrict__ recs, int n_edges) {
    int e = blockIdx.x * blockDim.x + threadIdx.x;
    if (e < n_edges) {
        int ie = ei[e];
        int bkt = (ie >> 7) * KPOS + ek[e];
        recs[off[bkt] + (int)rank[e]] = (unsigned)ej[e] | (((unsigned)ie & (NB - 1)) << 17);
    }
}

// ---------- gather: k-run register weights + LDS node-block accumulator ----------
__launch_bounds__(512, 8)
__global__ void gather_kernel(const unsigned* __restrict__ xb,
                              const unsigned* __restrict__ recs,
                              const int* __restrict__ boff,
                              const unsigned* __restrict__ wp,
                              const float* __restrict__ bias,
                              float* __restrict__ out, int n_nodes) {
    __shared__ float acc[NB * 64];           // 32 KB
    for (int t = threadIdx.x; t < NB * 16; t += blockDim.x)
        ((float4*)acc)[t] = make_float4(0.f, 0.f, 0.f, 0.f);
    __syncthreads();

    const int b = blockIdx.x;
    const int* bo = boff + b * KPOS;
    const int seg1 = bo[KPOS];

    const int lane = threadIdx.x & 63;
    const int half = lane >> 5;              // 0: edges p, p+2 ; 1: edges p+1, p+3
    const int g    = (lane >> 3) & 3;
    const int dp   = lane & 7;
    const int g8u  = g << 3;                 // x offset within node row (uints)
    const int och  = (g << 4) + dp;          // output channel (second = och+8)
    const unsigned wbase = (unsigned)(och << 2);

    const int wv  = threadIdx.x >> 6;
    const int nwv = blockDim.x >> 6;
    const int seg0 = bo[0];
    const int len  = seg1 - seg0;
    const int per  = (len + nwv - 1) / nwv;
    const int p0   = seg0 + wv * per;
    const int p1   = min(p0 + per, seg1);

    if (p0 < p1) {
        int k = 0;
        while (k < KPOS - 1 && bo[k + 1] <= p0) ++k;
        for (; k < KPOS; ++k) {
            int r0 = max(p0, bo[k]);
            int r1 = min(p1, bo[k + 1]);
            if (r0 >= p1) break;
            if (r0 >= r1) continue;
            const u32x4* wq = (const u32x4*)(wp + (k << 9) + wbase);
            u32x4 w00 = wq[0], w01 = wq[64], w10 = wq[8], w11 = wq[72];
            for (int p = r0; p < r1; p += 4) {
                int i0 = p + half, i1 = p + 2 + half;
                bool v0 = i0 < r1, v1 = i1 < r1;
                unsigned rec0 = recs[v0 ? i0 : r1 - 1];
                unsigned rec1 = recs[v1 ? i1 : r1 - 1];
                const u32x4* xp0 = (const u32x4*)(xb + ((rec0 & 0x1FFFFu) << 5) + g8u);
                const u32x4* xp1 = (const u32x4*)(xb + ((rec1 & 0x1FFFFu) << 5) + g8u);
                u32x4 xa0 = xp0[0], xc0 = xp0[1];
                u32x4 xa1 = xp1[0], xc1 = xp1[1];

                float s0 = 0.f, s1 = 0.f;
                DOT2(s0, xa0[0], w00[0]); DOT2(s0, xa0[1], w00[1]);
                DOT2(s0, xa0[2], w00[2]); DOT2(s0, xa0[3], w00[3]);
                DOT2(s0, xc0[0], w01[0]); DOT2(s0, xc0[1], w01[1]);
                DOT2(s0, xc0[2], w01[2]); DOT2(s0, xc0[3], w01[3]);
                DOT2(s1, xa0[0], w10[0]); DOT2(s1, xa0[1], w10[1]);
                DOT2(s1, xa0[2], w10[2]); DOT2(s1, xa0[3], w10[3]);
                DOT2(s1, xc0[0], w11[0]); DOT2(s1, xc0[1], w11[1]);
                DOT2(s1, xc0[2], w11[2]); DOT2(s1, xc0[3], w11[3]);
                if (v0) {
                    int il = (int)(rec0 >> 17);
                    atomicAdd(&acc[(il << 6) + och], s0);
                    atomicAdd(&acc[(il << 6) + och + 8], s1);
                }

                float t0 = 0.f, t1 = 0.f;
                DOT2(t0, xa1[0], w00[0]); DOT2(t0, xa1[1], w00[1]);
                DOT2(t0, xa1[2], w00[2]); DOT2(t0, xa1[3], w00[3]);
                DOT2(t0, xc1[0], w01[0]); DOT2(t0, xc1[1], w01[1]);
                DOT2(t0, xc1[2], w01[2]); DOT2(t0, xc1[3], w01[3]);
                DOT2(t1, xa1[0], w10[0]); DOT2(t1, xa1[1], w10[1]);
                DOT2(t1, xa1[2], w10[2]); DOT2(t1, xa1[3], w10[3]);
                DOT2(t1, xc1[0], w11[0]); DOT2(t1, xc1[1], w11[1]);
                DOT2(t1, xc1[2], w11[2]); DOT2(t1, xc1[3], w11[3]);
                if (v1) {
                    int il = (int)(rec1 >> 17);
                    atomicAdd(&acc[(il << 6) + och], t0);
                    atomicAdd(&acc[(il << 6) + och + 8], t1);
                }
            }
        }
    }
    __syncthreads();

    const int base = b * NB;
    for (int t = threadIdx.x; t < NB * 16; t += blockDim.x) {
        int node = base + (t >> 4);
        if (node < n_nodes) {
            float4 v = ((float4*)acc)[t];
            float4 bb = ((const float4*)bias)[t & 15];
            v.x += bb.x; v.y += bb.y; v.z += bb.z; v.w += bb.w;
            ((float4*)out)[(node << 4) + (t & 15)] = v;
        }
    }
}

static inline size_t al256(size_t x) { return (x + 255) & ~(size_t)255; }

extern "C" void kernel_launch(void* const* d_in, const int* in_sizes, int n_in,
                              void* d_out, int out_size, void* d_ws, size_t ws_size,
                              hipStream_t stream) {
    const float* input  = (const float*)d_in[0];
    const int*   ei     = (const int*)d_in[1];
    const int*   ej     = (const int*)d_in[2];
    const int*   ek     = (const int*)d_in[3];
    const float* weight = (const float*)d_in[5];
    const float* bias   = (const float*)d_in[6];

    const int n_edges = in_sizes[1];
    const int n_nodes = out_size / 64;
    const int nblocks = (n_nodes + NB - 1) / NB;
    const int nbk     = nblocks * KPOS;

    // workspace layout
    size_t off_o  = 0;
    size_t off_s  = al256((size_t)(nbk + 1) * 4);
    size_t cnt_o  = off_o + off_s;
    size_t cnt_s  = al256((size_t)nbk * 4);
    size_t par_o  = cnt_o + cnt_s;
    size_t par_s  = al256((size_t)SCAN_NB * 4);
    size_t rank_o = par_o + par_s;
    size_t rank_s = al256((size_t)n_edges * 2);
    size_t rec_o  = rank_o + rank_s;
    size_t rec_s  = al256((size_t)n_edges * 4);
    size_t wp_o   = rec_o + rec_s;
    size_t wp_s   = al256((size_t)WPACK_UINTS * 4);
    size_t xb_o   = wp_o + wp_s;
    size_t xb_s   = al256((size_t)n_nodes * 64 * 2);
    size_t need   = xb_o + xb_s;

    if (ws_size < need) {
        int blocks = (out_size + 255) / 256;
        hipLaunchKernelGGL(init_out_kernel, dim3(blocks), dim3(256), 0, stream,
                           (float*)d_out, bias, out_size);
        hipLaunchKernelGGL(edge_kernel_rawW, dim3(2048), dim3(256), 0, stream,
                           input, ei, ej, ek, weight, (float*)d_out, n_edges);
        return;
    }

    char* ws = (char*)d_ws;
    int*            off  = (int*)(ws + off_o);
    int*            cnt  = (int*)(ws + cnt_o);
    int*            par  = (int*)(ws + par_o);
    unsigned short* rank = (unsigned short*)(ws + rank_o);
    unsigned*       recs = (unsigned*)(ws + rec_o);
    unsigned*       wp   = (unsigned*)(ws + wp_o);
    unsigned*       xb   = (unsigned*)(ws + xb_o);

    const int eb = (n_edges + 255) / 256;
    const int nquads = n_nodes * 8;
    const int prep_range = max(nquads, max(nbk, WPACK_UINTS));
    const int chunk = (nbk + SCAN_NB - 1) / SCAN_NB;

    // 1) fused prep: zero bucket counts + repack weights + convert x
    hipLaunchKernelGGL(prep_kernel, dim3((prep_range + 255) / 256), dim3(256), 0, stream,
                       input, weight, xb, wp, cnt, nbk, nquads);
    // 2) counting sort by (i>>7, k) -> 4B records
    hipLaunchKernelGGL(rank_kernel, dim3(eb), dim3(256), 0, stream, ei, ek, cnt, rank, n_edges);
    hipLaunchKernelGGL(scanA_kernel, dim3(SCAN_NB), dim3(256), 0, stream, cnt, par, nbk, chunk);
    hipLaunchKernelGGL(scanB_kernel, dim3(1), dim3(SCAN_NB), 0, stream, par, off, nbk);
    hipLaunchKernelGGL(scanC_kernel, dim3(SCAN_NB), dim3(256), 0, stream, cnt, par, off, nbk, chunk);
    hipLaunchKernelGGL(fill_kernel, dim3(eb), dim3(256), 0, stream, ei, ej, ek, off, rank, recs, n_edges);

    // 3) gather: register weights per k-run, LDS accumulator, coalesced writeout
    hipLaunchKernelGGL(gather_kernel, dim3(nblocks), dim3(512), 0, stream,
                       xb, recs, off, wp, bias, (float*)d_out, n_nodes);
}

// Round 8
// 578.701 us; speedup vs baseline: 1.6912x; 1.6912x over previous
//
#include <hip/hip_runtime.h>
#include <hip/hip_bf16.h>

// GeneralConv: out[i[e]] += (group-wise 16x16 GEMV, weight slice k[e]) of input[j[e]], + bias.
// N=100000, E=2000000, C=64, K=27, G=4.
//
// R8: R7's (stripe=i>>4, k) sort retained (proven family: R6 passed with the
// same pattern), register-resident weights per k-run retained (kills the
// ~78us/CU per-edge LDS weight floor + all bank conflicts). Accumulation is
// now trivially correct: per-edge GLOBAL atomicAdd into bias-pre-initialized
// out (R4-proven mechanism). One wave owns a 16-node stripe => single writer
// per output line => atomics serialize locally in L2, no contention. The
// gather uses ZERO LDS: no syncthreads, full occupancy, no RMW hazards.

#define KPOS 27
#define STRIPE 16                     // nodes per wave
#define WPACK_UINTS (KPOS * 512)      // [k][q][gc][m] bf16-pairs: 13824 uints = 55296 B
#define SCAN_NB 256                   // blocks in multi-block scan

typedef unsigned u32x4 __attribute__((ext_vector_type(4)));

__device__ __forceinline__ unsigned packbf(float a, float b) {
    unsigned ua = (unsigned)__bfloat16_as_ushort(__float2bfloat16(a));
    unsigned ub = (unsigned)__bfloat16_as_ushort(__float2bfloat16(b));
    return ua | (ub << 16);
}

// acc += bf16lo(x)*bf16lo(w) + bf16hi(x)*bf16hi(w)  -- one VOP3P instruction
#define DOT2(A, X, W) asm("v_dot2_f32_bf16 %0, %1, %2, %0" : "+v"(A) : "v"(X), "v"(W))

// ---------- fallback (used only if ws too small) ----------
__global__ void init_out_kernel(float* __restrict__ out, const float* __restrict__ bias, int total) {
    int idx = blockIdx.x * blockDim.x + threadIdx.x;
    if (idx < total) out[idx] = bias[idx & 63];
}
__global__ void edge_kernel_rawW(const float* __restrict__ input, const int* __restrict__ ei,
                                 const int* __restrict__ ej, const int* __restrict__ ek,
                                 const float* __restrict__ weight, float* __restrict__ out, int n_edges) {
    const int lane = threadIdx.x & 63;
    const int g16 = lane & 48;
    const int d = lane & 15;
    int wave = (blockIdx.x * blockDim.x + threadIdx.x) >> 6;
    int n_waves = (gridDim.x * blockDim.x) >> 6;
    for (int e = wave; e < n_edges; e += n_waves) {
        int ie = ei[e], je = ej[e], ke = ek[e];
        float x = input[je * 64 + lane];
        float acc = 0.0f;
        #pragma unroll
        for (int c = 0; c < 16; ++c)
            acc += __shfl(x, g16 + c, 64) * weight[(g16 + c) * 432 + d * 27 + ke];
        atomicAdd(out + ie * 64 + lane, acc);
    }
}

// ---------- fused prep: zero bucket counts, bias-init out, repack weights, convert x ----------
__global__ void prep_kernel(const float* __restrict__ input, const float* __restrict__ weight,
                            const float* __restrict__ bias, float* __restrict__ out,
                            unsigned* __restrict__ xb, unsigned* __restrict__ wp,
                            int* __restrict__ cnt, int nbk, int nquads, int nout4) {
    int t = blockIdx.x * blockDim.x + threadIdx.x;
    if (t < nbk) cnt[t] = 0;
    if (t < WPACK_UINTS) {
        int k  = t >> 9;
        int r  = t & 511;
        int q  = r >> 8;
        int r2 = r & 255;
        int gc = r2 >> 2;
        int m  = r2 & 3;
        int g = gc >> 4, d = gc & 15;
        int c = (q * 4 + m) * 2;
        int ic = g * 16 + c;
        float f0 = weight[ic * 432 + d * 27 + k];
        float f1 = weight[(ic + 1) * 432 + d * 27 + k];
        wp[t] = packbf(f0, f1);
    }
    if (t < nquads) {
        const float4* in4 = (const float4*)input;
        float4 a = in4[2 * t], b = in4[2 * t + 1];
        uint4 o;
        o.x = packbf(a.x, a.y);
        o.y = packbf(a.z, a.w);
        o.z = packbf(b.x, b.y);
        o.w = packbf(b.z, b.w);
        ((uint4*)xb)[t] = o;
    }
    if (t < nout4) {
        ((float4*)out)[t] = ((const float4*)bias)[t & 15];
    }
}

// ---------- sort pipeline (key = (i>>4)*27 + k) ----------
__global__ void rank_kernel(const int* __restrict__ ei, const int* __restrict__ ek,
                            int* __restrict__ cnt,
                            unsigned short* __restrict__ rank, int n_edges) {
    int e = blockIdx.x * blockDim.x + threadIdx.x;
    if (e < n_edges) {
        int bkt = (ei[e] >> 4) * KPOS + ek[e];
        rank[e] = (unsigned short)atomicAdd(&cnt[bkt], 1);
    }
}

// phase A: per-block partial sums of cnt chunks
__global__ void scanA_kernel(const int* __restrict__ cnt, int* __restrict__ partial,
                             int n, int chunk) {
    __shared__ int red[256];
    int b = blockIdx.x;
    int lo = b * chunk, hi = min(lo + chunk, n);
    int s = 0;
    for (int v = lo + threadIdx.x; v < hi; v += 256) s += cnt[v];
    red[threadIdx.x] = s;
    __syncthreads();
    for (int d = 128; d > 0; d >>= 1) {
        if (threadIdx.x < d) red[threadIdx.x] += red[threadIdx.x + d];
        __syncthreads();
    }
    if (threadIdx.x == 0) partial[b] = red[0];
}

// phase B: single tiny block scans SCAN_NB partials (exclusive), writes off[n]=total
__global__ void scanB_kernel(int* __restrict__ partial, int* __restrict__ off, int n) {
    __shared__ int sums[SCAN_NB];
    int t = threadIdx.x;
    sums[t] = partial[t];
    __syncthreads();
    for (int d = 1; d < SCAN_NB; d <<= 1) {
        int val = (t >= d) ? sums[t - d] : 0;
        __syncthreads();
        sums[t] += val;
        __syncthreads();
    }
    partial[t] = (t == 0) ? 0 : sums[t - 1];   // exclusive
    if (t == SCAN_NB - 1) off[n] = sums[t];
}

// phase C: per-block exclusive scan of its chunk, offset by partial[b]
__global__ void scanC_kernel(const int* __restrict__ cnt, const int* __restrict__ partial,
                             int* __restrict__ off, int n, int chunk) {
    __shared__ int excl[256];
    int b = blockIdx.x;
    int lo = b * chunk, hi = min(lo + chunk, n);
    int per = (chunk + 255) >> 8;
    int tlo = lo + threadIdx.x * per;
    int thi = min(tlo + per, hi);
    int s = 0;
    for (int v = tlo; v < thi; ++v) s += cnt[v];
    excl[threadIdx.x] = s;
    __syncthreads();
    for (int d = 1; d < 256; d <<= 1) {
        int val = (threadIdx.x >= d) ? excl[threadIdx.x - d] : 0;
        __syncthreads();
        excl[threadIdx.x] += val;
        __syncthreads();
    }
    int run = partial[b] + ((threadIdx.x == 0) ? 0 : excl[threadIdx.x - 1]);
    for (int v = tlo; v < thi; ++v) { off[v] = run; run += cnt[v]; }
}

// fill: 4-byte record per edge: j | (i&15) << 17
__global__ void fill_kernel(const int* __restrict__ ei, const int* __restrict__ ej,
                            const int* __restrict__ ek, const int* __restrict__ off,
                            const unsigned short* __restrict__ rank,
                            unsigned* __restrict__ recs, int n_edges) {
    int e = blockIdx.x * blockDim.x + threadIdx.x;
    if (e < n_edges) {
        int ie = ei[e];
        int bkt = (ie >> 4) * KPOS + ek[e];
        recs[off[bkt] + (int)rank[e]] = (unsigned)ej[e] | (((unsigned)ie & (STRIPE - 1)) << 17);
    }
}

// ---------- gather: wave-owned stripe, k-run register weights, global atomic flush ----------
__launch_bounds__(256, 8)
__global__ void gather_kernel(const unsigned* __restrict__ xb,
                              const unsigned* __restrict__ recs,
                              const int* __restrict__ off,
                              const unsigned* __restrict__ wp,
                              float* __restrict__ out, int n_nodes) {
    const int lane = threadIdx.x & 63;
    const int g8u  = (lane & 48) >> 1;          // group x offset (uints)
    const int wv   = threadIdx.x >> 6;          // wave 0..3
    const int stripe = blockIdx.x * 4 + wv;
    const int nstripes = (n_nodes + STRIPE - 1) / STRIPE;
    if (stripe >= nstripes) return;

    const int nbase = stripe * STRIPE;          // first node of the stripe
    const int* bo = off + stripe * KPOS;

#define EDGE_DOT(RC, S) do {                                                  \
        const u32x4* xp_ = (const u32x4*)(xb + (((RC) & 0x1FFFFu) << 5) + g8u); \
        u32x4 xa_ = xp_[0], xc_ = xp_[1];                                     \
        DOT2(S, xa_[0], wa[0]); DOT2(S, xa_[1], wa[1]);                       \
        DOT2(S, xa_[2], wa[2]); DOT2(S, xa_[3], wa[3]);                       \
        DOT2(S, xc_[0], wb[0]); DOT2(S, xc_[1], wb[1]);                       \
        DOT2(S, xc_[2], wb[2]); DOT2(S, xc_[3], wb[3]);                       \
    } while (0)

    for (int k = 0; k < KPOS; ++k) {
        int r0 = bo[k], r1 = bo[k + 1];
        if (r0 >= r1) continue;
        // weights for this k-run -> registers (2 coalesced L2-hot loads)
        const u32x4* wq = (const u32x4*)(wp + (k << 9) + (lane << 2));
        u32x4 wa = wq[0], wb = wq[64];

        int e = r0;
        for (; e + 4 <= r1; e += 4) {
            unsigned rcA = recs[e],     rcB = recs[e + 1];
            unsigned rcC = recs[e + 2], rcD = recs[e + 3];
            const u32x4* xpA = (const u32x4*)(xb + ((rcA & 0x1FFFFu) << 5) + g8u);
            const u32x4* xpB = (const u32x4*)(xb + ((rcB & 0x1FFFFu) << 5) + g8u);
            const u32x4* xpC = (const u32x4*)(xb + ((rcC & 0x1FFFFu) << 5) + g8u);
            const u32x4* xpD = (const u32x4*)(xb + ((rcD & 0x1FFFFu) << 5) + g8u);
            u32x4 xaA = xpA[0], xcA = xpA[1];
            u32x4 xaB = xpB[0], xcB = xpB[1];
            u32x4 xaC = xpC[0], xcC = xpC[1];
            u32x4 xaD = xpD[0], xcD = xpD[1];

            float sA = 0.f, sB = 0.f, sC = 0.f, sD = 0.f;
            DOT2(sA, xaA[0], wa[0]); DOT2(sA, xaA[1], wa[1]);
            DOT2(sA, xaA[2], wa[2]); DOT2(sA, xaA[3], wa[3]);
            DOT2(sA, xcA[0], wb[0]); DOT2(sA, xcA[1], wb[1]);
            DOT2(sA, xcA[2], wb[2]); DOT2(sA, xcA[3], wb[3]);
            DOT2(sB, xaB[0], wa[0]); DOT2(sB, xaB[1], wa[1]);
            DOT2(sB, xaB[2], wa[2]); DOT2(sB, xaB[3], wa[3]);
            DOT2(sB, xcB[0], wb[0]); DOT2(sB, xcB[1], wb[1]);
            DOT2(sB, xcB[2], wb[2]); DOT2(sB, xcB[3], wb[3]);
            DOT2(sC, xaC[0], wa[0]); DOT2(sC, xaC[1], wa[1]);
            DOT2(sC, xaC[2], wa[2]); DOT2(sC, xaC[3], wa[3]);
            DOT2(sC, xcC[0], wb[0]); DOT2(sC, xcC[1], wb[1]);
            DOT2(sC, xcC[2], wb[2]); DOT2(sC, xcC[3], wb[3]);
            DOT2(sD, xaD[0], wa[0]); DOT2(sD, xaD[1], wa[1]);
            DOT2(sD, xaD[2], wa[2]); DOT2(sD, xaD[3], wa[3]);
            DOT2(sD, xcD[0], wb[0]); DOT2(sD, xcD[1], wb[1]);
            DOT2(sD, xcD[2], wb[2]); DOT2(sD, xcD[3], wb[3]);

            atomicAdd(out + ((nbase + (int)(rcA >> 17)) << 6) + lane, sA);
            atomicAdd(out + ((nbase + (int)(rcB >> 17)) << 6) + lane, sB);
            atomicAdd(out + ((nbase + (int)(rcC >> 17)) << 6) + lane, sC);
            atomicAdd(out + ((nbase + (int)(rcD >> 17)) << 6) + lane, sD);
        }
        for (; e < r1; ++e) {
            unsigned rc = recs[e];
            float s = 0.f;
            EDGE_DOT(rc, s);
            atomicAdd(out + ((nbase + (int)(rc >> 17)) << 6) + lane, s);
        }
    }
#undef EDGE_DOT
}

static inline size_t al256(size_t x) { return (x + 255) & ~(size_t)255; }

extern "C" void kernel_launch(void* const* d_in, const int* in_sizes, int n_in,
                              void* d_out, int out_size, void* d_ws, size_t ws_size,
                              hipStream_t stream) {
    const float* input  = (const float*)d_in[0];
    const int*   ei     = (const int*)d_in[1];
    const int*   ej     = (const int*)d_in[2];
    const int*   ek     = (const int*)d_in[3];
    const float* weight = (const float*)d_in[5];
    const float* bias   = (const float*)d_in[6];

    const int n_edges = in_sizes[1];
    const int n_nodes = out_size / 64;
    const int nstripes = (n_nodes + STRIPE - 1) / STRIPE;
    const int nbk      = nstripes * KPOS;
    const int nblocks  = (nstripes + 3) / 4;

    // workspace layout
    size_t off_o  = 0;
    size_t off_s  = al256((size_t)(nbk + 1) * 4);
    size_t cnt_o  = off_o + off_s;
    size_t cnt_s  = al256((size_t)nbk * 4);
    size_t par_o  = cnt_o + cnt_s;
    size_t par_s  = al256((size_t)SCAN_NB * 4);
    size_t rank_o = par_o + par_s;
    size_t rank_s = al256((size_t)n_edges * 2);
    size_t rec_o  = rank_o + rank_s;
    size_t rec_s  = al256((size_t)n_edges * 4);
    size_t wp_o   = rec_o + rec_s;
    size_t wp_s   = al256((size_t)WPACK_UINTS * 4);
    size_t xb_o   = wp_o + wp_s;
    size_t xb_s   = al256((size_t)n_nodes * 64 * 2);
    size_t need   = xb_o + xb_s;

    if (ws_size < need) {
        int blocks = (out_size + 255) / 256;
        hipLaunchKernelGGL(init_out_kernel, dim3(blocks), dim3(256), 0, stream,
                           (float*)d_out, bias, out_size);
        hipLaunchKernelGGL(edge_kernel_rawW, dim3(2048), dim3(256), 0, stream,
                           input, ei, ej, ek, weight, (float*)d_out, n_edges);
        return;
    }

    char* ws = (char*)d_ws;
    int*            off  = (int*)(ws + off_o);
    int*            cnt  = (int*)(ws + cnt_o);
    int*            par  = (int*)(ws + par_o);
    unsigned short* rank = (unsigned short*)(ws + rank_o);
    unsigned*       recs = (unsigned*)(ws + rec_o);
    unsigned*       wp   = (unsigned*)(ws + wp_o);
    unsigned*       xb   = (unsigned*)(ws + xb_o);

    const int eb = (n_edges + 255) / 256;
    const int nquads = n_nodes * 8;
    const int nout4  = n_nodes * 16;
    const int prep_range = max(max(nquads, nout4), max(nbk, WPACK_UINTS));
    const int chunk = (nbk + SCAN_NB - 1) / SCAN_NB;

    // 1) fused prep: zero bucket counts + bias-init out + repack weights + convert x
    hipLaunchKernelGGL(prep_kernel, dim3((prep_range + 255) / 256), dim3(256), 0, stream,
                       input, weight, bias, (float*)d_out, xb, wp, cnt,
                       nbk, nquads, nout4);
    // 2) counting sort by (i>>4, k) -> 4B records
    hipLaunchKernelGGL(rank_kernel, dim3(eb), dim3(256), 0, stream, ei, ek, cnt, rank, n_edges);
    hipLaunchKernelGGL(scanA_kernel, dim3(SCAN_NB), dim3(256), 0, stream, cnt, par, nbk, chunk);
    hipLaunchKernelGGL(scanB_kernel, dim3(1), dim3(SCAN_NB), 0, stream, par, off, nbk);
    hipLaunchKernelGGL(scanC_kernel, dim3(SCAN_NB), dim3(256), 0, stream, cnt, par, off, nbk, chunk);
    hipLaunchKernelGGL(fill_kernel, dim3(eb), dim3(256), 0, stream, ei, ej, ek, off, rank, recs, n_edges);

    // 3) gather: wave-owned stripes, register weights, per-edge global atomic flush
    hipLaunchKernelGGL(gather_kernel, dim3(nblocks), dim3(256), 0, stream,
                       xb, recs, off, wp, (float*)d_out, n_nodes);
}